// Round 2
// baseline (421.159 us; speedup 1.0000x reference)
//
#include <hip/hip_runtime.h>

// TemplatePointwiseAttention, MI355X/gfx950.
// Folded-weight refactor (exact): Abar = Wq@Wk^T/8 per head, Mbar = Wv@Wo per
// head -> GEMM1 (K=128) + 4-way softmax + GEMM2 (K=256), all bf16 MFMA.
// R2: 32 pairs/block (LDS 32 KB -> 4 blocks/CU, 16 waves/CU vs 7 before);
//     prep rewritten with LDS staging (was ~170us of uncoalesced reads).

#define R_   384
#define P_   (R_ * R_)     // 147456 residue pairs
#define NBLK (P_ / 32)     // 4608 blocks, 32 pairs each

typedef __attribute__((ext_vector_type(8))) short  short8;   // 8 x bf16 MFMA frag
typedef __attribute__((ext_vector_type(4))) float  f32x4;    // MFMA accumulator

__device__ __forceinline__ unsigned short f2bf(float f) {
  unsigned u = __float_as_uint(f);
  unsigned r = ((u >> 16) & 1u) + 0x7FFFu;   // RNE
  return (unsigned short)((u + r) >> 16);
}
__device__ __forceinline__ float bf2f(unsigned short s) {
  return __uint_as_float(((unsigned)s) << 16);
}
// LDS layout for [p][c] tiles (p<32, c<256), bf16, pitch 256, XOR-swizzled in
// 16B blocks: handles both "lanes vary p" (attention) and MFMA A-frag reads.
__device__ __forceinline__ int swz(int p, int c) {
  return p * 256 + ((((c >> 3) ^ (p & 31)) << 3) | (c & 7));
}

// ---- K0: fold weights. 8 blocks x 256 threads, LDS-staged, coalesced. ----
// AbarT[(h*64+j)][i] = 0.125 * sum_c Wq[i][h*64+c] * Wk[j][h*64+c]
// MbarT[o][(h*64+j)] =         sum_c Wv[j][h*64+c] * Wo[h*64+c][o]
__global__ void prep_kernel(const float* __restrict__ Wq, const float* __restrict__ Wk,
                            const float* __restrict__ Wv, const float* __restrict__ Wo,
                            unsigned short* __restrict__ AbarT,
                            unsigned short* __restrict__ MbarT) {
  __shared__ float sA[128 * 65];   // Wq slice [i][c] pad65 | Wo slice [c][o] pitch128
  __shared__ float sB[64 * 65];    // Wk/Wv slice [j][c] pad65
  const int t = threadIdx.x;
  if (blockIdx.x < 4) {
    const int h = blockIdx.x;
    // stage Wq[:, h*64 .. +64] -> sA[i*65+c]
    for (int it = 0; it < 8; ++it) {
      int idx = it * 256 + t;                 // 2048 float4
      int row = idx >> 4, c4 = (idx & 15) << 2;
      float4 v = *(const float4*)(Wq + row * 256 + h * 64 + c4);
      sA[row * 65 + c4 + 0] = v.x; sA[row * 65 + c4 + 1] = v.y;
      sA[row * 65 + c4 + 2] = v.z; sA[row * 65 + c4 + 3] = v.w;
    }
    // stage Wk[:, h*64 .. +64] -> sB[j*65+c]
    for (int it = 0; it < 4; ++it) {
      int idx = it * 256 + t;                 // 1024 float4
      int row = idx >> 4, c4 = (idx & 15) << 2;
      float4 v = *(const float4*)(Wk + row * 256 + h * 64 + c4);
      sB[row * 65 + c4 + 0] = v.x; sB[row * 65 + c4 + 1] = v.y;
      sB[row * 65 + c4 + 2] = v.z; sB[row * 65 + c4 + 3] = v.w;
    }
    __syncthreads();
    const int i = t & 127, jh2 = t >> 7;      // lanes vary i -> coalesced store
    for (int jj = 0; jj < 32; ++jj) {
      int j = jh2 * 32 + jj;
      float acc = 0.f;
#pragma unroll 8
      for (int c = 0; c < 64; ++c) acc += sA[i * 65 + c] * sB[j * 65 + c];
      AbarT[(h * 64 + j) * 128 + i] = f2bf(acc * 0.125f);   // 1/sqrt(64) folded
    }
  } else {
    const int h = blockIdx.x - 4;
    // stage Wo[h*64 .. +64][:] -> sA[c*128+o]
    for (int it = 0; it < 8; ++it) {
      int idx = it * 256 + t;                 // 2048 float4
      int row = idx >> 5, o4 = (idx & 31) << 2;
      *(float4*)(sA + row * 128 + o4) = *(const float4*)(Wo + (h * 64 + row) * 128 + o4);
    }
    // stage Wv[:, h*64 .. +64] -> sB[j*65+c]
    for (int it = 0; it < 4; ++it) {
      int idx = it * 256 + t;
      int row = idx >> 4, c4 = (idx & 15) << 2;
      float4 v = *(const float4*)(Wv + row * 256 + h * 64 + c4);
      sB[row * 65 + c4 + 0] = v.x; sB[row * 65 + c4 + 1] = v.y;
      sB[row * 65 + c4 + 2] = v.z; sB[row * 65 + c4 + 3] = v.w;
    }
    __syncthreads();
    const int o = t & 127, jh2 = t >> 7;      // sA[c*128+o]: lanes stride-1, clean
    for (int jj = 0; jj < 32; ++jj) {
      int j = jh2 * 32 + jj;
      float acc = 0.f;
#pragma unroll 8
      for (int c = 0; c < 64; ++c) acc += sB[j * 65 + c] * sA[c * 128 + o];
      MbarT[o * 256 + h * 64 + j] = f2bf(acc);
    }
  }
}

// ---- main fused kernel: 32 pairs / block, 256 threads (4 waves) ----
__global__ __launch_bounds__(256, 4) void attn_kernel(
    const float* __restrict__ z2d, const float* __restrict__ t2d,
    const unsigned short* __restrict__ AbarT, const unsigned short* __restrict__ MbarT,
    const float* __restrict__ bo, float* __restrict__ out) {
  __shared__ __align__(16) unsigned short sT[32 * 256];  // tkv tile bf16, 16 KB
  __shared__ __align__(16) unsigned short sG[32 * 256];  // G then S, 16 KB

  const int tid = threadIdx.x;
  const int P0  = blockIdx.x * 32;

  // ---- stage tkv (t2d[t][P0+p][j]) -> sT, fp32->bf16, swizzled ----
#pragma unroll
  for (int it = 0; it < 8; ++it) {
    int f  = it * 256 + tid;        // 2048 float4 total
    int t  = f >> 9;
    int rr = f & 511;
    int p  = rr >> 4;
    int j4 = (rr & 15) << 2;
    const float4 v = *(const float4*)(t2d + (size_t)(t * P_ + P0 + p) * 64 + j4);
    ushort4 pk;
    pk.x = f2bf(v.x); pk.y = f2bf(v.y); pk.z = f2bf(v.z); pk.w = f2bf(v.w);
    *(ushort4*)(sT + swz(p, t * 64 + j4)) = pk;
  }
  // no barrier yet: sT/sG first read only after the post-GEMM1 barrier below

  const int wv_  = tid >> 6;
  const int mt   = wv_ >> 1;   // m-tile (pairs mt*16..+16)
  const int nh   = wv_ & 1;    // n-half (cols nh*128..+128)
  const int lane = tid & 63;
  const int l = lane & 15;     // MFMA: A row / B col / D col
  const int q = lane >> 4;     // MFMA quad: k-group / D row-group

  // ---- GEMM1: G(32x256) = Z(32x128) @ Abar(128x256), bf16 MFMA ----
  f32x4 acc[8];
#pragma unroll
  for (int i = 0; i < 8; ++i) acc[i] = f32x4{0.f, 0.f, 0.f, 0.f};
  const float* zrow = z2d + (size_t)(P0 + mt * 16 + l) * 128;
#pragma unroll
  for (int kk = 0; kk < 4; ++kk) {
    float4 za = *(const float4*)(zrow + kk * 32 + q * 8);
    float4 zb = *(const float4*)(zrow + kk * 32 + q * 8 + 4);
    short8 af;
    af[0] = (short)f2bf(za.x); af[1] = (short)f2bf(za.y);
    af[2] = (short)f2bf(za.z); af[3] = (short)f2bf(za.w);
    af[4] = (short)f2bf(zb.x); af[5] = (short)f2bf(zb.y);
    af[6] = (short)f2bf(zb.z); af[7] = (short)f2bf(zb.w);
    const unsigned short* bbase = AbarT + (size_t)(nh * 128 + l) * 128 + kk * 32 + q * 8;
#pragma unroll
    for (int nt = 0; nt < 8; ++nt) {
      short8 bf = *(const short8*)(bbase + nt * 2048);   // n = nh*128 + nt*16 + l
      acc[nt] = __builtin_amdgcn_mfma_f32_16x16x32_bf16(af, bf, acc[nt], 0, 0, 0);
    }
  }
  // D[m=q*4+r][n=l] -> G[p=mt*16+q*4+r][nh*128+nt*16+l]
#pragma unroll
  for (int nt = 0; nt < 8; ++nt) {
    int c = nh * 128 + nt * 16 + l;
#pragma unroll
    for (int r = 0; r < 4; ++r) {
      int p = mt * 16 + q * 4 + r;
      sG[swz(p, c)] = f2bf(acc[nt][r]);
    }
  }
  __syncthreads();

  // ---- attention: unit = (pair p, head h, j-half jh); partner = tid^1 ----
  {
    const int jh = tid & 1;
    const int p  = (tid >> 1) & 31;
    const int h  = tid >> 6;
    const int c0 = h * 64 + jh * 32;   // this thread's G/S column range
    const int t0 = jh * 32;            // this thread's j-offset inside each t-row
    float lg0 = 0.f, lg1 = 0.f, lg2 = 0.f, lg3 = 0.f;
#pragma unroll
    for (int jb = 0; jb < 32; jb += 4) {
      ushort4 g4 = *(const ushort4*)(sG + swz(p, c0 + jb));
      float g0 = bf2f(g4.x), g1 = bf2f(g4.y), g2 = bf2f(g4.z), g3 = bf2f(g4.w);
      ushort4 k0 = *(const ushort4*)(sT + swz(p, t0 + jb));
      ushort4 k1 = *(const ushort4*)(sT + swz(p, 64 + t0 + jb));
      ushort4 k2 = *(const ushort4*)(sT + swz(p, 128 + t0 + jb));
      ushort4 k3 = *(const ushort4*)(sT + swz(p, 192 + t0 + jb));
      lg0 += g0 * bf2f(k0.x) + g1 * bf2f(k0.y) + g2 * bf2f(k0.z) + g3 * bf2f(k0.w);
      lg1 += g0 * bf2f(k1.x) + g1 * bf2f(k1.y) + g2 * bf2f(k1.z) + g3 * bf2f(k1.w);
      lg2 += g0 * bf2f(k2.x) + g1 * bf2f(k2.y) + g2 * bf2f(k2.z) + g3 * bf2f(k2.w);
      lg3 += g0 * bf2f(k3.x) + g1 * bf2f(k3.y) + g2 * bf2f(k3.z) + g3 * bf2f(k3.w);
    }
    // combine j-halves (partner differs only in bit0 -> same wave)
    lg0 += __shfl_xor(lg0, 1);
    lg1 += __shfl_xor(lg1, 1);
    lg2 += __shfl_xor(lg2, 1);
    lg3 += __shfl_xor(lg3, 1);
    float mx = fmaxf(fmaxf(lg0, lg1), fmaxf(lg2, lg3));
    float e0 = __expf(lg0 - mx), e1 = __expf(lg1 - mx);
    float e2 = __expf(lg2 - mx), e3 = __expf(lg3 - mx);
    float inv = 1.f / (e0 + e1 + e2 + e3);
    e0 *= inv; e1 *= inv; e2 *= inv; e3 *= inv;
    // S[p][h*64+j] = sum_t w_t * tkv[p][t][j]; write own j-half only
#pragma unroll
    for (int jb = 0; jb < 32; jb += 4) {
      ushort4 k0 = *(const ushort4*)(sT + swz(p, t0 + jb));
      ushort4 k1 = *(const ushort4*)(sT + swz(p, 64 + t0 + jb));
      ushort4 k2 = *(const ushort4*)(sT + swz(p, 128 + t0 + jb));
      ushort4 k3 = *(const ushort4*)(sT + swz(p, 192 + t0 + jb));
      ushort4 sv;
      sv.x = f2bf(e0 * bf2f(k0.x) + e1 * bf2f(k1.x) + e2 * bf2f(k2.x) + e3 * bf2f(k3.x));
      sv.y = f2bf(e0 * bf2f(k0.y) + e1 * bf2f(k1.y) + e2 * bf2f(k2.y) + e3 * bf2f(k3.y));
      sv.z = f2bf(e0 * bf2f(k0.z) + e1 * bf2f(k1.z) + e2 * bf2f(k2.z) + e3 * bf2f(k3.z));
      sv.w = f2bf(e0 * bf2f(k0.w) + e1 * bf2f(k1.w) + e2 * bf2f(k2.w) + e3 * bf2f(k3.w));
      *(ushort4*)(sG + swz(p, c0 + jb)) = sv;
    }
  }
  __syncthreads();

  // ---- GEMM2: OUT(32x128) = S(32x256) @ Mbar(256x128) + bo ----
  // wave = (mt, nh): rows mt*16..+16, cols nh*64..+64 (4 n-tiles)
  f32x4 acc2[4];
#pragma unroll
  for (int nt = 0; nt < 4; ++nt) acc2[nt] = f32x4{0.f, 0.f, 0.f, 0.f};
#pragma unroll
  for (int kk = 0; kk < 8; ++kk) {
    const int cb = kk * 32 + q * 8;          // cb % 8 == 0 -> one 16B swizzle block
    const int p  = mt * 16 + l;
    short8 af2 = *(const short8*)(sG + p * 256 + (((cb >> 3) ^ (p & 31)) << 3));
    const unsigned short* mb = MbarT + (size_t)(nh * 64 + l) * 256 + cb;
#pragma unroll
    for (int nt = 0; nt < 4; ++nt) {
      short8 bf = *(const short8*)(mb + nt * 4096);      // n = nh*64 + nt*16 + l
      acc2[nt] = __builtin_amdgcn_mfma_f32_16x16x32_bf16(af2, bf, acc2[nt], 0, 0, 0);
    }
  }
#pragma unroll
  for (int nt = 0; nt < 4; ++nt) {
    const int col = nh * 64 + nt * 16 + l;
    const float b = bo[col];
#pragma unroll
    for (int r = 0; r < 4; ++r) {
      size_t row = (size_t)(P0 + mt * 16 + q * 4 + r);
      out[row * 128 + col] = acc2[nt][r] + b;
    }
  }
}

extern "C" void kernel_launch(void* const* d_in, const int* in_sizes, int n_in,
                              void* d_out, int out_size, void* d_ws, size_t ws_size,
                              hipStream_t stream) {
  const float* z2d = (const float*)d_in[0];
  const float* t2d = (const float*)d_in[1];
  const float* Wq  = (const float*)d_in[2];
  const float* Wk  = (const float*)d_in[3];
  const float* Wv  = (const float*)d_in[4];
  const float* Wo  = (const float*)d_in[5];
  const float* bo  = (const float*)d_in[6];

  unsigned short* AbarT = (unsigned short*)d_ws;           // 256*128 bf16 = 64 KB
  unsigned short* MbarT = AbarT + 256 * 128;               // 128*256 bf16 = 64 KB
  float* out = (float*)d_out;

  hipLaunchKernelGGL(prep_kernel, dim3(8), dim3(256), 0, stream,
                     Wq, Wk, Wv, Wo, AbarT, MbarT);
  hipLaunchKernelGGL(attn_kernel, dim3(NBLK), dim3(256), 0, stream,
                     z2d, t2d, AbarT, MbarT, bo, out);
}